// Round 9
// baseline (369.072 us; speedup 1.0000x reference)
//
#include <hip/hip_runtime.h>
#include <stdint.h>

#define DEV static __device__ __forceinline__

typedef _Float16 half8 __attribute__((ext_vector_type(8)));
typedef _Float16 half4 __attribute__((ext_vector_type(4)));
typedef float f32x4 __attribute__((ext_vector_type(4)));
typedef uint16_t u16x8 __attribute__((ext_vector_type(8)));

// Problem constants (B=2, S=2048, D=2048, H=16, HD=128)
constexpr int Bc = 2, Sc = 2048, Dc = 2048, Hc = 16, HDc = 128;
constexpr int D3c = 3 * Dc;   // 6144
constexpr int Mc = Bc * Sc;   // 4096

// -------- helpers --------
DEV void gl_lds16(const void* g, void* l) {
    // async 16B/lane global->LDS; LDS dest = wave-uniform base + lane*16
    __builtin_amdgcn_global_load_lds(
        (const __attribute__((address_space(1))) unsigned int*)g,
        (__attribute__((address_space(3))) unsigned int*)l,
        16, 0, 0);
}

// ======================= fused prep: cast x + transpose both W ===============
// One dispatch instead of three. Block-granular branch:
//   id <  4096          : cast x (f32 -> f16), 2048 elems/block
//   id <  4096+3072     : transpose Wqkv [2048 x 6144] -> wt1 [6144 x 2048]
//   else (1024 blocks)  : transpose Wo   [2048 x 2048] -> wt2 [2048 x 2048]
DEV void transpose_tile(const float* __restrict__ in, _Float16* __restrict__ out,
                        int R, int C, int bx, int by, int t)
{
    __shared__ float ls[64][64];                 // 16 KB, chunk-swizzled storage
    const int r0 = by * 64, c0 = bx * 64;
    {
        const int rr = t >> 4, lc = t & 15;
#pragma unroll
        for (int p = 0; p < 4; ++p) {
            int r = p * 16 + rr;
            int pc = lc ^ ((r >> 3) & 7);
            *(float4*)&ls[r][pc * 4] =
                *(const float4*)&in[(size_t)(r0 + r) * C + c0 + lc * 4];
        }
    }
    __syncthreads();
    {
        const int oc = t >> 3, ss = (t & 7) * 8;
#pragma unroll
        for (int p = 0; p < 2; ++p) {
            int c = p * 32 + oc;
            int lc = c >> 2, wi = c & 3;
            half8 hv;
#pragma unroll
            for (int j = 0; j < 8; ++j) {
                int r = ss + j;
                hv[j] = (_Float16)ls[r][(lc ^ ((r >> 3) & 7)) * 4 + wi];
            }
            *(half8*)&out[(size_t)(c0 + c) * R + r0 + ss] = hv;
        }
    }
}

__global__ __launch_bounds__(256) void prep_kernel(
    const float* __restrict__ x, const float* __restrict__ Wqkv,
    const float* __restrict__ Wo,
    _Float16* __restrict__ xb, _Float16* __restrict__ wt1,
    _Float16* __restrict__ wt2)
{
    const int id = blockIdx.x, t = threadIdx.x;
    if (id < 4096) {
        int i = id * 256 + t;
        const float4* p = (const float4*)x;
        float4 a = p[i * 2], b = p[i * 2 + 1];
        half8 hv;
        hv[0] = (_Float16)a.x; hv[1] = (_Float16)a.y; hv[2] = (_Float16)a.z; hv[3] = (_Float16)a.w;
        hv[4] = (_Float16)b.x; hv[5] = (_Float16)b.y; hv[6] = (_Float16)b.z; hv[7] = (_Float16)b.w;
        *(half8*)(xb + (size_t)i * 8) = hv;
    } else if (id < 4096 + 3072) {
        int id2 = id - 4096;                    // grid was (96 x, 32 y)
        transpose_tile(Wqkv, wt1, Dc, D3c, id2 % 96, id2 / 96, t);
    } else {
        int id3 = id - 7168;                    // grid was (32 x, 32 y)
        transpose_tile(Wo, wt2, Dc, Dc, id3 & 31, id3 >> 5, t);
    }
}

// ====== V transpose: qkv[b,s, h*384+256+d] -> vt[(bh*128+d)*2048 + s] ======
__global__ __launch_bounds__(256) void transpose_v_kernel(
    const uint16_t* __restrict__ qkv, uint16_t* __restrict__ vt)
{
    __shared__ uint16_t ls[64][64];              // 8 KB; 8x 16B chunks per row
    const int t = threadIdx.x;
    const int s0 = blockIdx.x * 64, d0 = blockIdx.y * 64, bh = blockIdx.z;
    const int b = bh >> 4, h = bh & 15;
    {
        const int sr = t >> 3, lc = t & 7;
#pragma unroll
        for (int p = 0; p < 2; ++p) {
            int s = p * 32 + sr;
            int pc = lc ^ ((s >> 3) & 7);
            *(u16x8*)&ls[s][pc * 8] =
                *(const u16x8*)&qkv[(size_t)(b * Sc + s0 + s) * D3c + h * 384 + 256 + d0 + lc * 8];
        }
    }
    __syncthreads();
    {
        const int od = t >> 3, ss = (t & 7) * 8;
#pragma unroll
        for (int p = 0; p < 2; ++p) {
            int d = p * 32 + od;
            int lc = d >> 3, wi = d & 7;
            u16x8 hv;
#pragma unroll
            for (int j = 0; j < 8; ++j) {
                int s = ss + j;
                hv[j] = ls[s][(lc ^ ((s >> 3) & 7)) * 8 + wi];
            }
            *(u16x8*)&vt[(size_t)(bh * HDc + d0 + d) * Sc + s0 + ss] = hv;
        }
    }
}

// ======================= GEMM: C[M,N] = A[M,K] @ Bt[N,K]^T + bias =======================
// FROZEN R0-VERIFIED STRUCTURE (101 us, MfmaUtil 48%, FETCH 103MB, 0 conflicts).
template <int BF16OUT>
__global__ __launch_bounds__(256, 2) void gemm_bt_kernel(
    const _Float16* __restrict__ A, const _Float16* __restrict__ Bt,
    const float* __restrict__ bias, void* __restrict__ Cout,
    int M, int N, int K)
{
    __shared__ __align__(16) char smem[32768];
    char* sA = smem;            // [128 rows][8 chunks16B] swizzled: chunk ^= row&7
    char* sB = smem + 16384;
    const int t = threadIdx.x, w = t >> 6, lane = t & 63;
    const int quad = lane >> 4, l15 = lane & 15;
    const int wr = w >> 1, wc = w & 1;
    const int n0 = blockIdx.x * 128, m0 = blockIdx.y * 128;

    const f32x4 vzero = {0.f, 0.f, 0.f, 0.f};
    f32x4 acc[4][4];
#pragma unroll
    for (int i = 0; i < 4; ++i)
#pragma unroll
        for (int j = 0; j < 4; ++j) acc[i][j] = vzero;

    const int kiters = K >> 6;
    for (int kk = 0; kk < kiters; ++kk) {
#pragma unroll
        for (int i = 0; i < 4; ++i) {
            int c = i * 256 + t;
            int row = c >> 3, kbs = c & 7, kact = kbs ^ (row & 7);
            gl_lds16(A + (size_t)(m0 + row) * K + kk * 64 + kact * 8,
                     sA + (i * 256 + w * 64) * 16);
        }
#pragma unroll
        for (int i = 0; i < 4; ++i) {
            int c = i * 256 + t;
            int row = c >> 3, kbs = c & 7, kact = kbs ^ (row & 7);
            gl_lds16(Bt + (size_t)(n0 + row) * K + kk * 64 + kact * 8,
                     sB + (i * 256 + w * 64) * 16);
        }
        __syncthreads();
#pragma unroll
        for (int ks = 0; ks < 2; ++ks) {
            half8 af[4], bf[4];
#pragma unroll
            for (int mt = 0; mt < 4; ++mt) {
                int row = wr * 64 + mt * 16 + l15;
                int kact = (ks * 4 + quad) ^ (l15 & 7);
                af[mt] = *(const half8*)(sA + row * 128 + kact * 16);
            }
#pragma unroll
            for (int nt = 0; nt < 4; ++nt) {
                int row = wc * 64 + nt * 16 + l15;
                int kact = (ks * 4 + quad) ^ (l15 & 7);
                bf[nt] = *(const half8*)(sB + row * 128 + kact * 16);
            }
#pragma unroll
            for (int mt = 0; mt < 4; ++mt)
#pragma unroll
                for (int nt = 0; nt < 4; ++nt)
                    acc[mt][nt] = __builtin_amdgcn_mfma_f32_16x16x32_f16(
                        af[mt], bf[nt], acc[mt][nt], 0, 0, 0);
        }
        __syncthreads();
    }

    // epilogue: C/D layout col=lane&15, row=quad*4+reg (m89-verified)
#pragma unroll
    for (int nt = 0; nt < 4; ++nt) {
        int col = n0 + wc * 64 + nt * 16 + l15;
        float bv = bias[col];
#pragma unroll
        for (int mt = 0; mt < 4; ++mt)
#pragma unroll
            for (int r = 0; r < 4; ++r) {
                int row = m0 + wr * 64 + mt * 16 + quad * 4 + r;
                float v = acc[mt][nt][r] + bv;
                if (BF16OUT) ((_Float16*)Cout)[(size_t)row * N + col] = (_Float16)v;
                else         ((float*)Cout)[(size_t)row * N + col] = v;
            }
    }
}

// ======================= flash attention (S^T orientation, QBLK=128) ===========
// grid (32 bh, 16 q-blocks) = 512 blocks; block 256 = 4 waves, EACH WAVE OWNS
// 32 q (2 sub-tiles of 16) -- THIS ROUND'S LEVER. R8 analysis: flash is
// LDS-read-pipe-bound (every wave reads the full 32KB K+V tile per iter;
// 8 waves x 32KB = 256KB/tile-iter per CU vs only ~460 MFMA cy/SIMD). With 2
// q-groups per wave, each kf/vf LDS fragment feeds TWO MFMAs: per-CU LDS-read
// cycles per unit work HALVED (4 waves x 32KB serves the same 128 q).
// VGPR ~190 -> 2 waves/SIMD (8 waves/CU) = 2 blocks/CU; dbuf K/V 64KB kept.
__global__ __launch_bounds__(256, 2) void flash_kernel(
    const _Float16* __restrict__ qkv, const _Float16* __restrict__ vt,
    _Float16* __restrict__ attn)
{
    __shared__ __align__(16) char smem[65536];
    // buffers: K [64 kv][16 chunks16B] swz ^(row&15); V [128 d][8 chunks16B] swz ^(row&7)
    char* sKc = smem;            char* sVc = smem + 16384;
    char* sKn = smem + 32768;    char* sVn = smem + 49152;

    const int t = threadIdx.x, w = t >> 6, lane = t & 63;   // w in 0..3
    const int quad = lane >> 4, l15 = lane & 15;
    const int bh = blockIdx.x;
    const int by = blockIdx.y;
    const int qt = (by < 8) ? 15 - by : by - 8;   // heavy-first + balanced pairs
    const int b = bh >> 4, h = bh & 15;
    const int q0 = qt * 128;
    // lane owns TWO q columns: qrow[g] = q0 + w*32 + g*16 + l15
    const int qbase = q0 + w * 32 + l15;

    // Q fragments straight from global (once per block), 2 q-groups
    half8 qf[2][4];
#pragma unroll
    for (int g = 0; g < 2; ++g)
#pragma unroll
        for (int ks = 0; ks < 4; ++ks) {
            const _Float16* p = qkv + (size_t)(b * Sc + qbase + g * 16) * D3c +
                                h * 384 + ks * 32 + quad * 8;
            qf[g][ks] = *(const half8*)p;
        }

    const f32x4 vzero = {0.f, 0.f, 0.f, 0.f};
    f32x4 o[2][8];              // O^T[g][d = dt*16 + quad*4 + r], q = qbase+g*16
#pragma unroll
    for (int g = 0; g < 2; ++g)
#pragma unroll
        for (int dt = 0; dt < 8; ++dt) o[g][dt] = vzero;
    float m_st[2] = {-1e30f, -1e30f}, l_st[2] = {0.f, 0.f};

    const float kScale = 0.08838834764831845f * 1.4426950408889634f; // 1/sqrt(128)*log2(e)
    const int nkt = 2 * qt + 2;

    // 256-thread staging (R0-verified addressing)
    auto stageKV = [&](char* sK, char* sV, int kt) {
#pragma unroll
        for (int i = 0; i < 4; ++i) {
            int c = i * 256 + t;
            int row = c >> 4, kbs = c & 15, kact = kbs ^ (row & 15);
            gl_lds16(qkv + (size_t)(b * Sc + kt * 64 + row) * D3c + h * 384 + 128 + kact * 8,
                     sK + (i * 256 + w * 64) * 16);
        }
#pragma unroll
        for (int i = 0; i < 4; ++i) {
            int c = i * 256 + t;
            int row = c >> 3, kbs = c & 7, kact = kbs ^ (row & 7);
            gl_lds16(vt + (size_t)(bh * HDc + row) * Sc + kt * 64 + kact * 8,
                     sV + (i * 256 + w * 64) * 16);
        }
    };

    stageKV(sKc, sVc, 0);
    __syncthreads();

    for (int kt = 0; kt < nkt; ++kt) {
        if (kt + 1 < nkt) stageKV(sKn, sVn, kt + 1);   // issue into other buffer

        // ---- S^T = K Q^T : per wave M=64 kv x N=32 q (2x16), K=128 d ----
        // each kf read feeds BOTH q-groups (LDS-read per q halved)
        f32x4 sf[2][4];
#pragma unroll
        for (int g = 0; g < 2; ++g)
#pragma unroll
            for (int kb = 0; kb < 4; ++kb) sf[g][kb] = vzero;
#pragma unroll
        for (int ks = 0; ks < 4; ++ks) {
#pragma unroll
            for (int kb = 0; kb < 4; ++kb) {
                int row = kb * 16 + l15;
                int slot = (ks * 4 + quad) ^ l15;
                half8 kf = *(const half8*)(sKc + row * 256 + slot * 16);
                sf[0][kb] = __builtin_amdgcn_mfma_f32_16x16x32_f16(kf, qf[0][ks], sf[0][kb], 0, 0, 0);
                sf[1][kb] = __builtin_amdgcn_mfma_f32_16x16x32_f16(kf, qf[1][ks], sf[1][kb], 0, 0, 0);
            }
        }

        // ---- online softmax per q-group: lane owns q=qbase+g*16 ----
        const bool domask = (kt >= 2 * qt);   // tiles overlapping the diagonal
        half4 pb[2][4];
#pragma unroll
        for (int g = 0; g < 2; ++g) {
            const int qr = qbase + g * 16;
            float rm = -1e30f;
#pragma unroll
            for (int kb = 0; kb < 4; ++kb)
#pragma unroll
                for (int r = 0; r < 4; ++r) {
                    float v = sf[g][kb][r] * kScale;
                    if (domask) {
                        int col = kt * 64 + kb * 16 + quad * 4 + r;
                        if (col > qr) v = -1e30f;
                    }
                    sf[g][kb][r] = v;
                    rm = fmaxf(rm, v);
                }
            rm = fmaxf(rm, __shfl_xor(rm, 16, 64));
            rm = fmaxf(rm, __shfl_xor(rm, 32, 64));
            float mn = fmaxf(m_st[g], rm);
            float alpha = __builtin_amdgcn_exp2f(m_st[g] - mn);
            m_st[g] = mn;

            float rs = 0.f;
#pragma unroll
            for (int kb = 0; kb < 4; ++kb)
#pragma unroll
                for (int r = 0; r < 4; ++r) {
                    float p = __builtin_amdgcn_exp2f(sf[g][kb][r] - mn);
                    rs += p;
                    pb[g][kb][r] = (_Float16)p;
                }
            rs += __shfl_xor(rs, 16, 64);
            rs += __shfl_xor(rs, 32, 64);
            l_st[g] = l_st[g] * alpha + rs;

#pragma unroll
            for (int dt = 0; dt < 8; ++dt)
#pragma unroll
                for (int r = 0; r < 4; ++r) o[g][dt][r] *= alpha;
        }

        // ---- O^T += V^T P^T : each vf read feeds BOTH q-groups ----
#pragma unroll
        for (int kb = 0; kb < 4; ++kb) {
#pragma unroll
            for (int dt = 0; dt < 8; ++dt) {
                int row = dt * 16 + l15;
                int slot = (kb * 2 + (quad >> 1)) ^ (l15 & 7);
                half4 vf = *(const half4*)(sVc + row * 128 + slot * 16 + (quad & 1) * 8);
                o[0][dt] = __builtin_amdgcn_mfma_f32_16x16x16f16(vf, pb[0][kb], o[0][dt], 0, 0, 0);
                o[1][dt] = __builtin_amdgcn_mfma_f32_16x16x16f16(vf, pb[1][kb], o[1][dt], 0, 0, 0);
            }
        }

        __syncthreads();   // drains next-tile stage + this tile's lds reads
        char* tp;
        tp = sKc; sKc = sKn; sKn = tp;
        tp = sVc; sVc = sVn; sVn = tp;
    }

    // ---- epilogue: O^T/l -> LDS transpose -> coalesced f16 store ----
    char* sO = smem;      // [128 q][272B rows] (17x16B, conflict-shifted) = 34816B
#pragma unroll
    for (int g = 0; g < 2; ++g) {
        float linv = 1.0f / l_st[g];
#pragma unroll
        for (int dt = 0; dt < 8; ++dt) {
            half4 hv;
#pragma unroll
            for (int r = 0; r < 4; ++r) hv[r] = (_Float16)(o[g][dt][r] * linv);
            *(half4*)(sO + (w * 32 + g * 16 + l15) * 272 + (dt * 16 + quad * 4) * 2) = hv;
        }
    }
    __syncthreads();
#pragma unroll
    for (int i = 0; i < 8; ++i) {
        int q = i * 16 + (t >> 4);
        int d = (t & 15) * 8;
        half8 hv = *(const half8*)(sO + q * 272 + d * 2);
        *(half8*)(attn + (size_t)(b * Sc + q0 + q) * Dc + h * HDc + d) = hv;
    }
}

// ======================= launch =======================
extern "C" void kernel_launch(void* const* d_in, const int* in_sizes, int n_in,
                              void* d_out, int out_size, void* d_ws, size_t ws_size,
                              hipStream_t stream)
{
    (void)in_sizes; (void)n_in; (void)out_size; (void)ws_size;
    const float* x    = (const float*)d_in[0];
    const float* Wqkv = (const float*)d_in[1];
    const float* bqkv = (const float*)d_in[2];
    const float* Wo   = (const float*)d_in[3];
    const float* bo   = (const float*)d_in[4];
    float* out = (float*)d_out;

    // workspace layout (f16 elems); attn aliases xb, vtg aliases wt1 (both dead by then)
    _Float16* xb  = (_Float16*)d_ws;                   // 4096*2048
    _Float16* wt1 = xb  + (size_t)Mc * Dc;             // 6144*2048 (Wqkv^T)
    _Float16* wt2 = wt1 + (size_t)D3c * Dc;            // 2048*2048 (Wo^T)
    _Float16* qkv = wt2 + (size_t)Dc * Dc;             // 4096*6144
    _Float16* vtg  = wt1;                              // 32*128*2048 (V^T), reuses wt1
    _Float16* attn = xb;                               // 4096*2048, reuses xb

    prep_kernel<<<8192, 256, 0, stream>>>(x, Wqkv, Wo, xb, wt1, wt2);
    gemm_bt_kernel<1><<<dim3(D3c / 128, Mc / 128), 256, 0, stream>>>(
        xb, wt1, bqkv, qkv, Mc, D3c, Dc);
    transpose_v_kernel<<<dim3(Sc / 64, 2, Bc * Hc), 256, 0, stream>>>(
        (const uint16_t*)qkv, (uint16_t*)vtg);
    flash_kernel<<<dim3(Bc * Hc, 16), 256, 0, stream>>>(qkv, vtg, attn);
    gemm_bt_kernel<0><<<dim3(Dc / 128, Mc / 128), 256, 0, stream>>>(
        attn, wt2, bo, out, Mc, Dc, Dc);
}

// Round 11
// 357.627 us; speedup vs baseline: 1.0320x; 1.0320x over previous
//
#include <hip/hip_runtime.h>
#include <stdint.h>

#define DEV static __device__ __forceinline__

typedef _Float16 half8 __attribute__((ext_vector_type(8)));
typedef _Float16 half4 __attribute__((ext_vector_type(4)));
typedef float f32x4 __attribute__((ext_vector_type(4)));
typedef uint16_t u16x8 __attribute__((ext_vector_type(8)));

// Problem constants (B=2, S=2048, D=2048, H=16, HD=128)
constexpr int Bc = 2, Sc = 2048, Dc = 2048, Hc = 16, HDc = 128;
constexpr int D3c = 3 * Dc;   // 6144
constexpr int Mc = Bc * Sc;   // 4096

// V^T chunk map (fused transpose): V value (b,h,s,d) lives as 8-s-element
// 16B chunks: chunk q = d*256 + s/8, stored at physical slot
//   qkv + (b*2048 + (q>>4))*6144 + h*384 + 256 + (q&15)*8 + (s&7)
// inside the (otherwise dead) natural V region of the qkv buffer.
// gemm<1> epilogue WRITES this layout for V col-blocks; flash stages V
// through the same map. transpose_v kernel eliminated.
// (R10 resubmit: prior run died at container level; full bounds/race audit
// found no kernel-side crash path -- infra flake.)

// -------- helpers --------
DEV void gl_lds16(const void* g, void* l) {
    // async 16B/lane global->LDS; LDS dest = wave-uniform base + lane*16
    __builtin_amdgcn_global_load_lds(
        (const __attribute__((address_space(1))) unsigned int*)g,
        (__attribute__((address_space(3))) unsigned int*)l,
        16, 0, 0);
}

// ======================= fused prep: cast x + transpose both W ===============
DEV void transpose_tile(const float* __restrict__ in, _Float16* __restrict__ out,
                        int R, int C, int bx, int by, int t)
{
    __shared__ float ls[64][64];                 // 16 KB, chunk-swizzled storage
    const int r0 = by * 64, c0 = bx * 64;
    {
        const int rr = t >> 4, lc = t & 15;
#pragma unroll
        for (int p = 0; p < 4; ++p) {
            int r = p * 16 + rr;
            int pc = lc ^ ((r >> 3) & 7);
            *(float4*)&ls[r][pc * 4] =
                *(const float4*)&in[(size_t)(r0 + r) * C + c0 + lc * 4];
        }
    }
    __syncthreads();
    {
        const int oc = t >> 3, ss = (t & 7) * 8;
#pragma unroll
        for (int p = 0; p < 2; ++p) {
            int c = p * 32 + oc;
            int lc = c >> 2, wi = c & 3;
            half8 hv;
#pragma unroll
            for (int j = 0; j < 8; ++j) {
                int r = ss + j;
                hv[j] = (_Float16)ls[r][(lc ^ ((r >> 3) & 7)) * 4 + wi];
            }
            *(half8*)&out[(size_t)(c0 + c) * R + r0 + ss] = hv;
        }
    }
}

__global__ __launch_bounds__(256) void prep_kernel(
    const float* __restrict__ x, const float* __restrict__ Wqkv,
    const float* __restrict__ Wo,
    _Float16* __restrict__ xb, _Float16* __restrict__ wt1,
    _Float16* __restrict__ wt2)
{
    const int id = blockIdx.x, t = threadIdx.x;
    if (id < 4096) {
        int i = id * 256 + t;
        const float4* p = (const float4*)x;
        float4 a = p[i * 2], b = p[i * 2 + 1];
        half8 hv;
        hv[0] = (_Float16)a.x; hv[1] = (_Float16)a.y; hv[2] = (_Float16)a.z; hv[3] = (_Float16)a.w;
        hv[4] = (_Float16)b.x; hv[5] = (_Float16)b.y; hv[6] = (_Float16)b.z; hv[7] = (_Float16)b.w;
        *(half8*)(xb + (size_t)i * 8) = hv;
    } else if (id < 4096 + 3072) {
        int id2 = id - 4096;                    // grid was (96 x, 32 y)
        transpose_tile(Wqkv, wt1, Dc, D3c, id2 % 96, id2 / 96, t);
    } else {
        int id3 = id - 7168;                    // grid was (32 x, 32 y)
        transpose_tile(Wo, wt2, Dc, Dc, id3 & 31, id3 >> 5, t);
    }
}

// ======================= GEMM: C[M,N] = A[M,K] @ Bt[N,K]^T + bias =======================
// FROZEN R0-VERIFIED STRUCTURE (101 us, MfmaUtil 48%, FETCH 103MB, 0 conflicts).
// gemm<1> epilogue writes the per-head V col-blocks (n0%384==256, exactly
// 128-wide/128-aligned) in V^T chunk layout into the same physical V region
// (see map at top). Blocks write disjoint (s-chunk x d x head) sets ->
// race-free. 16 half4 stores replace 64 scalar stores in those blocks.
template <int BF16OUT>
__global__ __launch_bounds__(256, 2) void gemm_bt_kernel(
    const _Float16* __restrict__ A, const _Float16* __restrict__ Bt,
    const float* __restrict__ bias, void* __restrict__ Cout,
    int M, int N, int K)
{
    __shared__ __align__(16) char smem[32768];
    char* sA = smem;            // [128 rows][8 chunks16B] swizzled: chunk ^= row&7
    char* sB = smem + 16384;
    const int t = threadIdx.x, w = t >> 6, lane = t & 63;
    const int quad = lane >> 4, l15 = lane & 15;
    const int wr = w >> 1, wc = w & 1;
    const int n0 = blockIdx.x * 128, m0 = blockIdx.y * 128;

    const f32x4 vzero = {0.f, 0.f, 0.f, 0.f};
    f32x4 acc[4][4];
#pragma unroll
    for (int i = 0; i < 4; ++i)
#pragma unroll
        for (int j = 0; j < 4; ++j) acc[i][j] = vzero;

    const int kiters = K >> 6;
    for (int kk = 0; kk < kiters; ++kk) {
#pragma unroll
        for (int i = 0; i < 4; ++i) {
            int c = i * 256 + t;
            int row = c >> 3, kbs = c & 7, kact = kbs ^ (row & 7);
            gl_lds16(A + (size_t)(m0 + row) * K + kk * 64 + kact * 8,
                     sA + (i * 256 + w * 64) * 16);
        }
#pragma unroll
        for (int i = 0; i < 4; ++i) {
            int c = i * 256 + t;
            int row = c >> 3, kbs = c & 7, kact = kbs ^ (row & 7);
            gl_lds16(Bt + (size_t)(n0 + row) * K + kk * 64 + kact * 8,
                     sB + (i * 256 + w * 64) * 16);
        }
        __syncthreads();
#pragma unroll
        for (int ks = 0; ks < 2; ++ks) {
            half8 af[4], bf[4];
#pragma unroll
            for (int mt = 0; mt < 4; ++mt) {
                int row = wr * 64 + mt * 16 + l15;
                int kact = (ks * 4 + quad) ^ (l15 & 7);
                af[mt] = *(const half8*)(sA + row * 128 + kact * 16);
            }
#pragma unroll
            for (int nt = 0; nt < 4; ++nt) {
                int row = wc * 64 + nt * 16 + l15;
                int kact = (ks * 4 + quad) ^ (l15 & 7);
                bf[nt] = *(const half8*)(sB + row * 128 + kact * 16);
            }
#pragma unroll
            for (int mt = 0; mt < 4; ++mt)
#pragma unroll
                for (int nt = 0; nt < 4; ++nt)
                    acc[mt][nt] = __builtin_amdgcn_mfma_f32_16x16x32_f16(
                        af[mt], bf[nt], acc[mt][nt], 0, 0, 0);
        }
        __syncthreads();
    }

    // epilogue: C/D layout col=lane&15, row=quad*4+reg (m89-verified)
    const bool isV = BF16OUT && ((n0 % 384) == 256);
    if (isV) {
        // V col-block: store transposed chunks (see map at top of file)
        const int hh = n0 / 384;
        _Float16* vb = (_Float16*)Cout;   // qkv buffer
#pragma unroll
        for (int nt = 0; nt < 4; ++nt) {
            int d = wc * 64 + nt * 16 + l15;
            float bv = bias[n0 + d];
#pragma unroll
            for (int mt = 0; mt < 4; ++mt) {
                int rowb = m0 + wr * 64 + mt * 16 + quad * 4;   // s0 (r=0)
                int bb = rowb >> 11, sg = rowb & 2047;
                int q = d * 256 + (sg >> 3);
                half4 hv;
#pragma unroll
                for (int r = 0; r < 4; ++r) hv[r] = (_Float16)(acc[mt][nt][r] + bv);
                _Float16* dst = vb + (size_t)(bb * Sc + (q >> 4)) * D3c +
                                hh * 384 + 256 + (q & 15) * 8 + (sg & 7);
                *(half4*)dst = hv;
            }
        }
    } else {
#pragma unroll
        for (int nt = 0; nt < 4; ++nt) {
            int col = n0 + wc * 64 + nt * 16 + l15;
            float bv = bias[col];
#pragma unroll
            for (int mt = 0; mt < 4; ++mt)
#pragma unroll
                for (int r = 0; r < 4; ++r) {
                    int row = m0 + wr * 64 + mt * 16 + quad * 4 + r;
                    float v = acc[mt][nt][r] + bv;
                    if (BF16OUT) ((_Float16*)Cout)[(size_t)row * N + col] = (_Float16)v;
                    else         ((float*)Cout)[(size_t)row * N + col] = v;
                }
        }
    }
}

// ======================= flash attention (S^T orientation, QBLK=128) ===========
// R7-EXACT STRUCTURE (session-best 360.4): grid (32 bh, 16 q-blocks); block
// 512 = 8 waves x 16 q rows; single-buffer K/V (36 KB); no setprio; heavy/light
// paired qt remap. ONLY change: V staged straight from the fused V^T chunk
// layout inside qkv (same LDS image as before -> PV code untouched).
__global__ __launch_bounds__(512, 4) void flash_kernel(
    const _Float16* __restrict__ qkv, _Float16* __restrict__ attn)
{
    __shared__ __align__(16) char smem[36864];
    char* sK = smem;            // [64 kv][16 chunks16B] swizzled ^(row&15)
    char* sV = smem + 16384;    // [128 d][8 chunks16B]  swizzled ^(row&7)

    const int t = threadIdx.x, w = t >> 6, lane = t & 63;   // w in 0..7
    const int quad = lane >> 4, l15 = lane & 15;
    const int bh = blockIdx.x;
    const int by = blockIdx.y;
    const int qt = (by < 8) ? 15 - by : by - 8;   // heavy-first + balanced pairs
    const int b = bh >> 4, h = bh & 15;
    const int q0 = qt * 128;
    const int qrow = q0 + w * 16 + l15;      // this lane's q column (S^T orientation)

    // Q fragments straight from global (once per block)
    half8 qf[4];
#pragma unroll
    for (int ks = 0; ks < 4; ++ks) {
        const _Float16* p = qkv + (size_t)(b * Sc + qrow) * D3c +
                            h * 384 + ks * 32 + quad * 8;
        qf[ks] = *(const half8*)p;
    }

    const f32x4 vzero = {0.f, 0.f, 0.f, 0.f};
    f32x4 o[8];                 // O^T[d = dt*16 + quad*4 + r][q = l15-col]
#pragma unroll
    for (int dt = 0; dt < 8; ++dt) o[dt] = vzero;
    float m_st = -1e30f, l_st = 0.f;   // per-lane stats for q = qrow

    const float kScale = 0.08838834764831845f * 1.4426950408889634f; // 1/sqrt(128)*log2(e)
    const int nkt = 2 * qt + 2;

    for (int kt = 0; kt < nkt; ++kt) {
        // ---- stage K tile [64 kv][128 d]: 1024 chunks over 512 threads ----
#pragma unroll
        for (int i = 0; i < 2; ++i) {
            int c = i * 512 + t;
            int row = c >> 4, kbs = c & 15, kact = kbs ^ (row & 15);
            gl_lds16(qkv + (size_t)(b * Sc + kt * 64 + row) * D3c + h * 384 + 128 + kact * 8,
                     sK + (i * 512 + w * 64) * 16);
        }
        // ---- stage Vt tile [128 d][64 kv] from fused chunk layout ----
#pragma unroll
        for (int i = 0; i < 2; ++i) {
            int c = i * 512 + t;
            int row = c >> 3, kbs = c & 7, kact = kbs ^ (row & 7);
            int q = row * 256 + kt * 8 + kact;     // V^T chunk id (d=row, s-chunk)
            gl_lds16(qkv + (size_t)(b * Sc + (q >> 4)) * D3c + h * 384 + 256 + (q & 15) * 8,
                     sV + (i * 512 + w * 64) * 16);
        }
        __syncthreads();

        // ---- S^T = K Q^T : per wave M=64 kv x N=16 q, K=128 d ----
        f32x4 sf[4];
#pragma unroll
        for (int kb = 0; kb < 4; ++kb) sf[kb] = vzero;
#pragma unroll
        for (int ks = 0; ks < 4; ++ks) {
#pragma unroll
            for (int kb = 0; kb < 4; ++kb) {
                int row = kb * 16 + l15;
                int slot = (ks * 4 + quad) ^ l15;
                half8 kf = *(const half8*)(sK + row * 256 + slot * 16);
                sf[kb] = __builtin_amdgcn_mfma_f32_16x16x32_f16(kf, qf[ks], sf[kb], 0, 0, 0);
            }
        }

        // ---- online softmax: lane owns q=qrow, kv = kt*64 + kb*16+quad*4+r ----
        const bool domask = (kt >= 2 * qt);   // tiles overlapping the diagonal
        float rm = -1e30f;
#pragma unroll
        for (int kb = 0; kb < 4; ++kb)
#pragma unroll
            for (int r = 0; r < 4; ++r) {
                float v = sf[kb][r] * kScale;
                if (domask) {
                    int col = kt * 64 + kb * 16 + quad * 4 + r;
                    if (col > qrow) v = -1e30f;
                }
                sf[kb][r] = v;
                rm = fmaxf(rm, v);
            }
        rm = fmaxf(rm, __shfl_xor(rm, 16, 64));
        rm = fmaxf(rm, __shfl_xor(rm, 32, 64));
        float mn = fmaxf(m_st, rm);
        float alpha = __builtin_amdgcn_exp2f(m_st - mn);
        m_st = mn;

        // P^T pack: exp2(s-m) -> f16; C-layout(kv=quad*4+r) == B-layout(k=quad*4+j)
        half4 pb[4];
        float rs = 0.f;
#pragma unroll
        for (int kb = 0; kb < 4; ++kb)
#pragma unroll
            for (int r = 0; r < 4; ++r) {
                float p = __builtin_amdgcn_exp2f(sf[kb][r] - mn);
                rs += p;
                pb[kb][r] = (_Float16)p;
            }
        rs += __shfl_xor(rs, 16, 64);
        rs += __shfl_xor(rs, 32, 64);
        l_st = l_st * alpha + rs;

        // rescale O^T (alpha per-lane scalar: all o elements share q=qrow)
#pragma unroll
        for (int dt = 0; dt < 8; ++dt)
#pragma unroll
            for (int r = 0; r < 4; ++r) o[dt][r] *= alpha;

        // ---- O^T += V^T P^T (mfma 16x16x16: A=V^T rows, B=P^T in-register) ----
#pragma unroll
        for (int kb = 0; kb < 4; ++kb) {
#pragma unroll
            for (int dt = 0; dt < 8; ++dt) {
                int row = dt * 16 + l15;
                int slot = (kb * 2 + (quad >> 1)) ^ (l15 & 7);
                half4 vf = *(const half4*)(sV + row * 128 + slot * 16 + (quad & 1) * 8);
                o[dt] = __builtin_amdgcn_mfma_f32_16x16x16f16(vf, pb[kb], o[dt], 0, 0, 0);
            }
        }
        __syncthreads();   // LDS reads done before restaging
    }

    // ---- epilogue: O^T/l -> LDS transpose -> coalesced f16 store ----
    char* sO = smem;      // [128 q][272B rows] (17x16B, conflict-shifted) = 34816B
    float linv = 1.0f / l_st;
#pragma unroll
    for (int dt = 0; dt < 8; ++dt) {
        half4 hv;
#pragma unroll
        for (int r = 0; r < 4; ++r) hv[r] = (_Float16)(o[dt][r] * linv);
        *(half4*)(sO + (w * 16 + l15) * 272 + (dt * 16 + quad * 4) * 2) = hv;
    }
    __syncthreads();
#pragma unroll
    for (int i = 0; i < 4; ++i) {
        int q = i * 32 + (t >> 4);
        int d = (t & 15) * 8;
        half8 hv = *(const half8*)(sO + q * 272 + d * 2);
        *(half8*)(attn + (size_t)(b * Sc + q0 + q) * Dc + h * HDc + d) = hv;
    }
}

// ======================= launch =======================
extern "C" void kernel_launch(void* const* d_in, const int* in_sizes, int n_in,
                              void* d_out, int out_size, void* d_ws, size_t ws_size,
                              hipStream_t stream)
{
    (void)in_sizes; (void)n_in; (void)out_size; (void)ws_size;
    const float* x    = (const float*)d_in[0];
    const float* Wqkv = (const float*)d_in[1];
    const float* bqkv = (const float*)d_in[2];
    const float* Wo   = (const float*)d_in[3];
    const float* bo   = (const float*)d_in[4];
    float* out = (float*)d_out;

    // workspace layout (f16 elems); attn aliases xb (dead by then)
    _Float16* xb  = (_Float16*)d_ws;                   // 4096*2048
    _Float16* wt1 = xb  + (size_t)Mc * Dc;             // 6144*2048 (Wqkv^T)
    _Float16* wt2 = wt1 + (size_t)D3c * Dc;            // 2048*2048 (Wo^T)
    _Float16* qkv = wt2 + (size_t)Dc * Dc;             // 4096*6144 (V region holds V^T chunks)
    _Float16* attn = xb;                               // 4096*2048, reuses xb

    prep_kernel<<<8192, 256, 0, stream>>>(x, Wqkv, Wo, xb, wt1, wt2);
    gemm_bt_kernel<1><<<dim3(D3c / 128, Mc / 128), 256, 0, stream>>>(
        xb, wt1, bqkv, qkv, Mc, D3c, Dc);
    flash_kernel<<<dim3(Bc * Hc, 16), 512, 0, stream>>>(qkv, attn);
    gemm_bt_kernel<0><<<dim3(Dc / 128, Mc / 128), 256, 0, stream>>>(
        attn, wt2, bo, out, Mc, Dc, Dc);
}